// Round 4
// baseline (3084.279 us; speedup 1.0000x reference)
//
#include <hip/hip_runtime.h>
#include <math.h>

#define TS 2048
#define TT 64

// LDS float offsets
#define XT0  0      // x tile buffer 0: [64 t][64 c]
#define XT1  4096   // x tile buffer 1
#define H0O  8192   // h0[2][64] (parity double-buffer)
#define H1O  8320   // h1[2][64]
#define SCRO 8448   // epilogue scratch (96 floats)
#define LDSF 8544

// Raw barrier: LDS-ordering only, NO vmcnt drain (stage prefetch stays in flight)
#define BAR() do { asm volatile("s_waitcnt lgkmcnt(0)" ::: "memory"); __builtin_amdgcn_s_barrier(); } while(0)

__device__ __forceinline__ float sigmoidf_(float v){ return 1.0f/(1.0f+__expf(-v)); }
__device__ __forceinline__ float tanhf_(float v){
  v = fminf(15.0f, fmaxf(-15.0f, v));
  float e = __expf(2.0f*v);
  return (e-1.0f)/(e+1.0f);
}
// quad (4-lane) butterfly adds on the VALU pipe via DPP quad_perm
__device__ __forceinline__ float qadd_xor1(float v){
  return v + __int_as_float(__builtin_amdgcn_update_dpp(0, __float_as_int(v), 0xB1, 0xF, 0xF, true));
}
__device__ __forceinline__ float qadd_xor2(float v){
  return v + __int_as_float(__builtin_amdgcn_update_dpp(0, __float_as_int(v), 0x4E, 0xF, 0xF, true));
}

__device__ __forceinline__ void fma4(float& acc, const float4 a, const float4 v){
  acc = fmaf(a.x, v.x, acc); acc = fmaf(a.y, v.y, acc);
  acc = fmaf(a.z, v.z, acc); acc = fmaf(a.w, v.w, acc);
}

// 10 waves = 640 threads:
//   waves 0-3: layer-0, wave w -> rows 16w..16w+15; lane = 4*row_local + quarter
//              each thread: all 3 gates (r,z,n), 16-MAC quarter-dots, DPP quad reduce
//   waves 4-7: layer-1, same
//   wave 8   : attention (lane o: full 64-dot vs attn_w1[o])
//   wave 9   : x stage (coalesced loads at tt==0, transposed LDS write at tt==32)
// ONE barrier per timestep; h0/h1 parity double-buffered.
__global__ __launch_bounds__(640, 1)
void gru_attn_fused(const float* __restrict__ x,
                    const float* __restrict__ w_ih0, const float* __restrict__ w_hh0,
                    const float* __restrict__ b_ih0, const float* __restrict__ b_hh0,
                    const float* __restrict__ w_ih1, const float* __restrict__ w_hh1,
                    const float* __restrict__ b_ih1, const float* __restrict__ b_hh1,
                    const float* __restrict__ attn_w1, const float* __restrict__ attn_b1,
                    const float* __restrict__ attn_w2, const float* __restrict__ attn_b2,
                    const float* __restrict__ ln_g, const float* __restrict__ ln_b,
                    const float* __restrict__ head_w1, const float* __restrict__ head_b1,
                    const float* __restrict__ head_w2, const float* __restrict__ head_b2,
                    float* __restrict__ out)
{
  __shared__ float lds[LDSF];
  const int tid  = threadIdx.x;
  const int b    = blockIdx.x;
  const int wid  = tid >> 6;
  const int lane = tid & 63;
  const float* xb = x + (size_t)b * 64 * TS;

  const bool isGate  = (wid < 8);
  const bool isAttn  = (wid == 8);
  const int  l       = (wid >> 2) & 1;          // gate-wave layer
  const int  row     = ((wid & 3) << 4) + (lane >> 2);  // 0..63 within layer
  const int  q16     = (lane & 3) << 4;         // quarter offset in floats

  // Role-overloaded register array (shared allocation across roles):
  //   gate: W[0..3]=w_ih(r) W[4..7]=w_ih(z) W[8..11]=w_ih(n)
  //         W[12..15]=w_hh(r) W[16..19]=w_hh(z) W[20..23]=w_hh(n)  (quarter rows)
  //   attn: W[0..15] = attn_w1 row
  //   stage: W[0..15] = x prefetch pipeline
  float4 W[24];
  float brz_r=0.f, brz_z=0.f, bin_=0.f, bhn_=0.f, b1o=0.f, w2o=0.f, b2v=0.f;

  if (isGate) {
    const float* bih = l ? w_ih1 : w_ih0;
    const float* bhh = l ? w_hh1 : w_hh0;
    #pragma unroll
    for (int i=0;i<4;i++){
      W[i]    = *(const float4*)(bih + (      row)*64 + q16 + 4*i);
      W[4+i]  = *(const float4*)(bih + ( 64 + row)*64 + q16 + 4*i);
      W[8+i]  = *(const float4*)(bih + (128 + row)*64 + q16 + 4*i);
      W[12+i] = *(const float4*)(bhh + (      row)*64 + q16 + 4*i);
      W[16+i] = *(const float4*)(bhh + ( 64 + row)*64 + q16 + 4*i);
      W[20+i] = *(const float4*)(bhh + (128 + row)*64 + q16 + 4*i);
    }
    const float* bi = l ? b_ih1 : b_ih0;
    const float* bh = l ? b_hh1 : b_hh0;
    brz_r = bi[row]      + bh[row];
    brz_z = bi[64+row]   + bh[64+row];
    bin_  = bi[128+row];
    bhn_  = bh[128+row];
  } else if (isAttn) {
    #pragma unroll
    for (int i=0;i<16;i++) W[i] = *(const float4*)(attn_w1 + lane*64 + 4*i);
    b1o = attn_b1[lane]; w2o = attn_w2[lane]; b2v = attn_b2[0];
  }

  // prologue: zero h buffers (256 floats), stage x tile 0 coalesced+transpose
  if (tid < 256) lds[H0O + tid] = 0.f;
  if (tid < 256) {
    const int c = tid >> 2, t0 = (tid & 3) << 4;
    #pragma unroll
    for (int m=0;m<4;m++){
      float4 v = *(const float4*)(xb + c*TS + t0 + 4*m);
      lds[XT0 + (t0+4*m+0)*64 + c] = v.x;
      lds[XT0 + (t0+4*m+1)*64 + c] = v.y;
      lds[XT0 + (t0+4*m+2)*64 + c] = v.z;
      lds[XT0 + (t0+4*m+3)*64 + c] = v.w;
    }
  }
  __syncthreads();

  float am = -1e30f, aZ = 0.f, aP = 0.f;   // online softmax (wave 8)

  // Skew: iter it computes L0@t=it, L1@t=it-1, attn@t=it-2.
  // Reads from parity rb=it&1, writes to wb=rb^1.
  #pragma unroll 1
  for (int it = 0; it < TS + 2; ++it) {
    const int rb   = it & 1;
    const int wb   = rb ^ 1;
    const int tile = it >> 6;
    const int xsel = tile & 1;
    const int tt   = it & 63;

    if (isGate) {
      const bool act = (l==0) ? (it < TS) : (it >= 1 && it <= TS);
      if (act) {
        const float* xv;
        const float* hv;
        if (l==0) { xv = &lds[(xsel?XT1:XT0) + tt*64 + q16]; hv = &lds[H0O + rb*64 + q16]; }
        else      { xv = &lds[H0O + rb*64 + q16];            hv = &lds[H1O + rb*64 + q16]; }
        float ar=0.f,az=0.f,an=0.f,cr=0.f,cz=0.f,cn=0.f;
        #pragma unroll
        for (int i=0;i<4;i++){
          const float4 vx = ((const float4*)xv)[i];
          const float4 vh = ((const float4*)hv)[i];
          fma4(ar, W[i],    vx);
          fma4(az, W[4+i],  vx);
          fma4(an, W[8+i],  vx);
          fma4(cr, W[12+i], vh);
          fma4(cz, W[16+i], vh);
          fma4(cn, W[20+i], vh);
        }
        const float sr = qadd_xor2(qadd_xor1(ar + cr));
        const float sz = qadd_xor2(qadd_xor1(az + cz));
        const float xn = qadd_xor2(qadd_xor1(an));
        const float hn = qadd_xor2(qadd_xor1(cn));
        const float r  = sigmoidf_(sr + brz_r);
        const float z  = sigmoidf_(sz + brz_z);
        const float n  = tanhf_((xn + bin_) + r*(hn + bhn_));
        const int hbo  = l ? H1O : H0O;
        const float hold = lds[hbo + rb*64 + row];
        if ((lane & 3) == 0) lds[hbo + wb*64 + row] = n + z*(hold - n);
      }
    } else if (isAttn) {
      if (it >= 2) {
        const float* hv = &lds[H1O + rb*64];
        float acc0=0.f, acc1=0.f, acc2=0.f, acc3=0.f;
        #pragma unroll
        for (int i=0;i<4;i++){
          const float4 v0 = ((const float4*)hv)[4*i+0];
          const float4 v1 = ((const float4*)hv)[4*i+1];
          const float4 v2 = ((const float4*)hv)[4*i+2];
          const float4 v3 = ((const float4*)hv)[4*i+3];
          fma4(acc0, W[4*i+0], v0);
          fma4(acc1, W[4*i+1], v1);
          fma4(acc2, W[4*i+2], v2);
          fma4(acc3, W[4*i+3], v3);
        }
        const float a = tanhf_(((acc0+acc1)+(acc2+acc3)) + b1o);
        float sp = w2o * a;
        #pragma unroll
        for (int m=1;m<64;m<<=1) sp += __shfl_xor(sp, m, 64);
        const float s   = sp + b2v;
        const float h1v = lds[H1O + rb*64 + lane];
        const float mn  = fmaxf(am, s);
        const float sc  = __expf(am - mn);
        const float p   = __expf(s - mn);
        aZ = aZ*sc + p;
        aP = aP*sc + p*h1v;
        am = mn;
      }
    } else { // stage wave (wid 9)
      if (tile <= 30) {
        if (tt == 0) {
          // coalesced: inst k loads rows 4k..4k+3, lanes 0-15 contiguous 256B
          const float* src = xb + (lane>>4)*TS + (tile+1)*64 + ((lane&15)<<2);
          #pragma unroll
          for (int k=0;k<16;k++) W[k] = *(const float4*)(src + (size_t)k*4*TS);
        } else if (tt == 32) {
          // transpose into the buffer the NEXT tile reads (xsel^1)
          float* dst = &lds[xsel ? XT0 : XT1];
          const int c0 = lane >> 4, t4 = (lane & 15) << 2;
          #pragma unroll
          for (int k=0;k<16;k++){
            dst[(t4+0)*64 + 4*k + c0] = W[k].x;
            dst[(t4+1)*64 + 4*k + c0] = W[k].y;
            dst[(t4+2)*64 + 4*k + c0] = W[k].z;
            dst[(t4+3)*64 + 4*k + c0] = W[k].w;
          }
        }
      }
    }
    BAR();
  }

  // ---------------- epilogue ----------------
  if (isAttn) {
    const float pooled = aP / aZ;
    float mu = pooled;
    #pragma unroll
    for (int m=1;m<64;m<<=1) mu += __shfl_xor(mu, m, 64);
    mu *= (1.0f/64.0f);
    const float d = pooled - mu;
    float var = d*d;
    #pragma unroll
    for (int m=1;m<64;m<<=1) var += __shfl_xor(var, m, 64);
    var *= (1.0f/64.0f);
    const float y = d * rsqrtf(var + 1e-5f) * ln_g[lane] + ln_b[lane];
    lds[SCRO + lane] = y;
  }
  __syncthreads();
  if (tid < 32) {
    const float* hw = head_w1 + tid*64;
    float acc = head_b1[tid];
    #pragma unroll
    for (int k=0;k<16;k++){
      const float4 w4 = ((const float4*)hw)[k];
      acc += w4.x*lds[SCRO+4*k+0] + w4.y*lds[SCRO+4*k+1]
           + w4.z*lds[SCRO+4*k+2] + w4.w*lds[SCRO+4*k+3];
    }
    const float u = 0.5f*acc*(1.0f + erff(acc*0.70710678118654752f)); // exact GELU
    lds[SCRO + 64 + tid] = u;
  }
  __syncthreads();
  if (tid < 8) {
    const float* hw = head_w2 + tid*32;
    float acc = head_b2[tid];
    #pragma unroll
    for (int k=0;k<8;k++){
      const float4 w4 = ((const float4*)hw)[k];
      acc += w4.x*lds[SCRO+64+4*k+0] + w4.y*lds[SCRO+64+4*k+1]
           + w4.z*lds[SCRO+64+4*k+2] + w4.w*lds[SCRO+64+4*k+3];
    }
    out[b*8 + tid] = acc;
  }
}

extern "C" void kernel_launch(void* const* d_in, const int* in_sizes, int n_in,
                              void* d_out, int out_size, void* d_ws, size_t ws_size,
                              hipStream_t stream) {
  (void)in_sizes; (void)n_in; (void)d_ws; (void)ws_size; (void)out_size;
  const float* x       = (const float*)d_in[0];
  const float* w_ih0   = (const float*)d_in[1];
  const float* w_hh0   = (const float*)d_in[2];
  const float* b_ih0   = (const float*)d_in[3];
  const float* b_hh0   = (const float*)d_in[4];
  const float* w_ih1   = (const float*)d_in[5];
  const float* w_hh1   = (const float*)d_in[6];
  const float* b_ih1   = (const float*)d_in[7];
  const float* b_hh1   = (const float*)d_in[8];
  const float* attn_w1 = (const float*)d_in[9];
  const float* attn_b1 = (const float*)d_in[10];
  const float* attn_w2 = (const float*)d_in[11];
  const float* attn_b2 = (const float*)d_in[12];
  const float* ln_g    = (const float*)d_in[13];
  const float* ln_b    = (const float*)d_in[14];
  const float* head_w1 = (const float*)d_in[15];
  const float* head_b1 = (const float*)d_in[16];
  const float* head_w2 = (const float*)d_in[17];
  const float* head_b2 = (const float*)d_in[18];
  hipLaunchKernelGGL(gru_attn_fused, dim3(256), dim3(640), 0, stream,
                     x, w_ih0, w_hh0, b_ih0, b_hh0, w_ih1, w_hh1, b_ih1, b_hh1,
                     attn_w1, attn_b1, attn_w2, attn_b2, ln_g, ln_b,
                     head_w1, head_b1, head_w2, head_b2, (float*)d_out);
}

// Round 5
// 2118.755 us; speedup vs baseline: 1.4557x; 1.4557x over previous
//
#include <hip/hip_runtime.h>
#include <math.h>

#define TS 2048

typedef float f32x2 __attribute__((ext_vector_type(2)));

// Swizzled column index: each 16-float quarter padded to stride 24 (96B, 16B-aligned).
// Quarter bases hit banks {0,24,16,8} -> 4 disjoint width-4 bank groups -> no conflicts.
#define SWZ(c) (((((c)>>4))*24) + ((c)&15))
#define RSTR 96   // padded row stride (floats) for a 64-float vector

// LDS float offsets
#define XT0  0       // x tile 0: [64 t][96]
#define XT1  6144    // x tile 1
#define H0O  12288   // h0[2][96] parity double-buffer
#define H1O  12480   // h1[2][96]
#define SCRO 12672   // epilogue scratch
#define LDSF 12772

// Raw barrier: LDS-ordering only, NO vmcnt drain (stage prefetch stays in flight)
#define BAR() do { asm volatile("s_waitcnt lgkmcnt(0)" ::: "memory"); __builtin_amdgcn_s_barrier(); } while(0)

__device__ __forceinline__ float sigmoidf_(float v){ return __builtin_amdgcn_rcpf(1.0f+__expf(-v)); }
__device__ __forceinline__ float tanhf_(float v){
  v = fminf(15.0f, fmaxf(-15.0f, v));
  const float e = __expf(2.0f*v);
  return (e-1.0f)*__builtin_amdgcn_rcpf(e+1.0f);
}

// pk-fma helper on float2 vectors (lowers to v_pk_fma_f32)
__device__ __forceinline__ void pkfma(f32x2& acc, const f32x2 w, const f32x2 v){
  acc = __builtin_elementwise_fma(w, v, acc);
}

// 10 waves = 640 threads:
//   waves 0-3: layer-0. wave g=wid&3 -> rows g*16..g*16+15; lane = q*16 + r
//              thread: all 3 gates (r,z,n), both mats, 16-col quarter q -> 96 MACs (48 pk-fma)
//   waves 4-7: layer-1, same
//   wave 8   : attention (lane o: full 64-dot vs attn_w1[o], pk-fma)
//   wave 9   : x stage (coalesced global loads at tt==0, swizzled LDS write at tt==32)
// ONE barrier per timestep; h0/h1 parity double-buffered.
__global__ __launch_bounds__(640, 1)
void gru_attn_fused(const float* __restrict__ x,
                    const float* __restrict__ w_ih0, const float* __restrict__ w_hh0,
                    const float* __restrict__ b_ih0, const float* __restrict__ b_hh0,
                    const float* __restrict__ w_ih1, const float* __restrict__ w_hh1,
                    const float* __restrict__ b_ih1, const float* __restrict__ b_hh1,
                    const float* __restrict__ attn_w1, const float* __restrict__ attn_b1,
                    const float* __restrict__ attn_w2, const float* __restrict__ attn_b2,
                    const float* __restrict__ ln_g, const float* __restrict__ ln_b,
                    const float* __restrict__ head_w1, const float* __restrict__ head_b1,
                    const float* __restrict__ head_w2, const float* __restrict__ head_b2,
                    float* __restrict__ out)
{
  __shared__ float lds[LDSF];
  const int tid  = threadIdx.x;
  const int b    = blockIdx.x;
  const int wid  = tid >> 6;
  const int lane = tid & 63;
  const float* xb = x + (size_t)b * 64 * TS;

  const bool isGate = (wid < 8);
  const bool isAttn = (wid == 8);
  const int  l      = (wid >> 2) & 1;                  // gate-wave layer
  const int  row    = ((wid & 3) << 4) + (lane & 15);  // 0..63 within layer
  const int  q      = lane >> 4;                       // quarter 0..3
  const int  q16    = q << 4;                          // col offset (unpadded)
  const int  q24    = q * 24;                          // col offset (padded LDS)
  const int  srow   = SWZ(row);                        // swizzled h index for this row

  // Role-overloaded register array:
  //   gate: W[0..3]=w_ih(r) W[4..7]=w_ih(z) W[8..11]=w_ih(n)
  //         W[12..15]=w_hh(r) W[16..19]=w_hh(z) W[20..23]=w_hh(n)  (quarter rows, 96 floats)
  //   attn: W[0..15] = attn_w1 row (64 floats)
  //   stage: W[0..15] = x prefetch pipeline
  float4 W[24];
  float brz_r=0.f, brz_z=0.f, bin_=0.f, bhn_=0.f, b1o=0.f, w2o=0.f, b2v=0.f;

  if (isGate) {
    const float* bih = l ? w_ih1 : w_ih0;
    const float* bhh = l ? w_hh1 : w_hh0;
    #pragma unroll
    for (int i=0;i<4;i++){
      W[i]    = *(const float4*)(bih + (      row)*64 + q16 + 4*i);
      W[4+i]  = *(const float4*)(bih + ( 64 + row)*64 + q16 + 4*i);
      W[8+i]  = *(const float4*)(bih + (128 + row)*64 + q16 + 4*i);
      W[12+i] = *(const float4*)(bhh + (      row)*64 + q16 + 4*i);
      W[16+i] = *(const float4*)(bhh + ( 64 + row)*64 + q16 + 4*i);
      W[20+i] = *(const float4*)(bhh + (128 + row)*64 + q16 + 4*i);
    }
    const float* bi = l ? b_ih1 : b_ih0;
    const float* bh = l ? b_hh1 : b_hh0;
    brz_r = bi[row]      + bh[row];
    brz_z = bi[64+row]   + bh[64+row];
    bin_  = bi[128+row];
    bhn_  = bh[128+row];
  } else if (isAttn) {
    #pragma unroll
    for (int i=0;i<16;i++) W[i] = *(const float4*)(attn_w1 + lane*64 + 4*i);
    b1o = attn_b1[lane]; w2o = attn_w2[lane]; b2v = attn_b2[0];
  }

  // prologue: zero h buffers (384 floats incl. pads), stage x tile 0 (swizzled transpose)
  if (tid < 384) lds[H0O + tid] = 0.f;
  if (tid < 256) {
    const int c = tid >> 2, t0 = (tid & 3) << 4;
    const int sc = SWZ(c);
    #pragma unroll
    for (int m=0;m<4;m++){
      float4 v = *(const float4*)(xb + c*TS + t0 + 4*m);
      lds[XT0 + (t0+4*m+0)*RSTR + sc] = v.x;
      lds[XT0 + (t0+4*m+1)*RSTR + sc] = v.y;
      lds[XT0 + (t0+4*m+2)*RSTR + sc] = v.z;
      lds[XT0 + (t0+4*m+3)*RSTR + sc] = v.w;
    }
  }
  __syncthreads();

  float am = -1e30f, aZ = 0.f, aP = 0.f;   // online softmax (wave 8)

  // Skew: iter it computes L0@t=it, L1@t=it-1, attn@t=it-2.
  // h(t) of a layer is written during its compute-iter into buffer wb=rb^1.
  #pragma unroll 1
  for (int it = 0; it < TS + 2; ++it) {
    const int rb   = it & 1;
    const int wb   = rb ^ 1;
    const int tile = it >> 6;
    const int xsel = tile & 1;
    const int tt   = it & 63;

    if (isGate) {
      const bool act = (l==0) ? (it < TS) : (it >= 1 && it <= TS);
      if (act) {
        const float* xv;
        const float* hv;
        if (l==0) { xv = &lds[(xsel?XT1:XT0) + tt*RSTR + q24]; hv = &lds[H0O + rb*RSTR + q24]; }
        else      { xv = &lds[H0O + rb*RSTR + q24];            hv = &lds[H1O + rb*RSTR + q24]; }
        f32x2 ar={0.f,0.f}, az={0.f,0.f}, an={0.f,0.f};
        f32x2 cr={0.f,0.f}, cz={0.f,0.f}, cn={0.f,0.f};
        #pragma unroll
        for (int i=0;i<4;i++){
          const float4 vx = ((const float4*)xv)[i];
          const float4 vh = ((const float4*)hv)[i];
          const f32x2 x0 = {vx.x, vx.y}, x1 = {vx.z, vx.w};
          const f32x2 h0 = {vh.x, vh.y}, h1 = {vh.z, vh.w};
          pkfma(ar, (f32x2){W[i].x,    W[i].y},    x0);
          pkfma(ar, (f32x2){W[i].z,    W[i].w},    x1);
          pkfma(az, (f32x2){W[4+i].x,  W[4+i].y},  x0);
          pkfma(az, (f32x2){W[4+i].z,  W[4+i].w},  x1);
          pkfma(an, (f32x2){W[8+i].x,  W[8+i].y},  x0);
          pkfma(an, (f32x2){W[8+i].z,  W[8+i].w},  x1);
          pkfma(cr, (f32x2){W[12+i].x, W[12+i].y}, h0);
          pkfma(cr, (f32x2){W[12+i].z, W[12+i].w}, h1);
          pkfma(cz, (f32x2){W[16+i].x, W[16+i].y}, h0);
          pkfma(cz, (f32x2){W[16+i].z, W[16+i].w}, h1);
          pkfma(cn, (f32x2){W[20+i].x, W[20+i].y}, h0);
          pkfma(cn, (f32x2){W[20+i].z, W[20+i].w}, h1);
        }
        float sr = (ar.x+ar.y)+(cr.x+cr.y);
        float sz = (az.x+az.y)+(cz.x+cz.y);
        float xn = an.x+an.y;
        float hn = cn.x+cn.y;
        sr += __shfl_xor(sr,16); sz += __shfl_xor(sz,16);
        xn += __shfl_xor(xn,16); hn += __shfl_xor(hn,16);
        sr += __shfl_xor(sr,32); sz += __shfl_xor(sz,32);
        xn += __shfl_xor(xn,32); hn += __shfl_xor(hn,32);
        const float r = sigmoidf_(sr + brz_r);
        const float z = sigmoidf_(sz + brz_z);
        const float n = tanhf_((xn + bin_) + r*(hn + bhn_));
        const int hbo = l ? H1O : H0O;
        const float hold = lds[hbo + rb*RSTR + srow];
        if (q == 0) lds[hbo + wb*RSTR + srow] = n + z*(hold - n);  // (1-z)n + z h
      }
    } else if (isAttn) {
      if (it >= 2) {
        const float* hv = &lds[H1O + rb*RSTR];
        f32x2 p0={0.f,0.f}, p1={0.f,0.f};
        #pragma unroll
        for (int qq=0;qq<4;qq++){
          const float4* hp = (const float4*)(hv + qq*24);
          #pragma unroll
          for (int i=0;i<4;i++){
            const float4 v = hp[i];
            const float4 w4 = W[qq*4+i];
            pkfma(p0, (f32x2){w4.x, w4.y}, (f32x2){v.x, v.y});
            pkfma(p1, (f32x2){w4.z, w4.w}, (f32x2){v.z, v.w});
          }
        }
        const float a = tanhf_(((p0.x+p0.y)+(p1.x+p1.y)) + b1o);
        float sp = w2o * a;
        #pragma unroll
        for (int m=1;m<64;m<<=1) sp += __shfl_xor(sp, m, 64);
        const float s   = sp + b2v;
        const float h1v = lds[H1O + rb*RSTR + SWZ(lane)];
        const float mn  = fmaxf(am, s);
        const float sc  = __expf(am - mn);
        const float p   = __expf(s - mn);
        aZ = aZ*sc + p;
        aP = aP*sc + p*h1v;
        am = mn;
      }
    } else { // stage wave (wid 9)
      if (tile <= 30) {
        if (tt == 0) {
          // coalesced: inst k loads x[c=4k+(lane>>4)][t4..t4+3], lanes 0-15 contiguous 256B
          const float* src = xb + (lane>>4)*TS + (tile+1)*64 + ((lane&15)<<2);
          #pragma unroll
          for (int k=0;k<16;k++) W[k] = *(const float4*)(src + (size_t)k*4*TS);
        } else if (tt == 32) {
          // swizzled transpose into the buffer the NEXT tile reads (xsel^1)
          float* dst = &lds[xsel ? XT0 : XT1];
          const int c0 = lane >> 4, t4 = (lane & 15) << 2;
          #pragma unroll
          for (int k=0;k<16;k++){
            const int oc = (k>>2)*24 + 4*(k&3) + c0;   // SWZ(4k + c0)
            dst[(t4+0)*RSTR + oc] = W[k].x;
            dst[(t4+1)*RSTR + oc] = W[k].y;
            dst[(t4+2)*RSTR + oc] = W[k].z;
            dst[(t4+3)*RSTR + oc] = W[k].w;
          }
        }
      }
    }
    BAR();
  }

  // ---------------- epilogue ----------------
  if (isAttn) {
    const float pooled = aP / aZ;
    float mu = pooled;
    #pragma unroll
    for (int m=1;m<64;m<<=1) mu += __shfl_xor(mu, m, 64);
    mu *= (1.0f/64.0f);
    const float d = pooled - mu;
    float var = d*d;
    #pragma unroll
    for (int m=1;m<64;m<<=1) var += __shfl_xor(var, m, 64);
    var *= (1.0f/64.0f);
    const float y = d * rsqrtf(var + 1e-5f) * ln_g[lane] + ln_b[lane];
    lds[SCRO + lane] = y;
  }
  __syncthreads();
  if (tid < 32) {
    const float* hw = head_w1 + tid*64;
    float acc = head_b1[tid];
    #pragma unroll
    for (int k=0;k<16;k++){
      const float4 w4 = ((const float4*)hw)[k];
      acc += w4.x*lds[SCRO+4*k+0] + w4.y*lds[SCRO+4*k+1]
           + w4.z*lds[SCRO+4*k+2] + w4.w*lds[SCRO+4*k+3];
    }
    const float u = 0.5f*acc*(1.0f + erff(acc*0.70710678118654752f)); // exact GELU
    lds[SCRO + 64 + tid] = u;
  }
  __syncthreads();
  if (tid < 8) {
    const float* hw = head_w2 + tid*32;
    float acc = head_b2[tid];
    #pragma unroll
    for (int k=0;k<8;k++){
      const float4 w4 = ((const float4*)hw)[k];
      acc += w4.x*lds[SCRO+64+4*k+0] + w4.y*lds[SCRO+64+4*k+1]
           + w4.z*lds[SCRO+64+4*k+2] + w4.w*lds[SCRO+64+4*k+3];
    }
    out[b*8 + tid] = acc;
  }
}

extern "C" void kernel_launch(void* const* d_in, const int* in_sizes, int n_in,
                              void* d_out, int out_size, void* d_ws, size_t ws_size,
                              hipStream_t stream) {
  (void)in_sizes; (void)n_in; (void)d_ws; (void)ws_size; (void)out_size;
  const float* x       = (const float*)d_in[0];
  const float* w_ih0   = (const float*)d_in[1];
  const float* w_hh0   = (const float*)d_in[2];
  const float* b_ih0   = (const float*)d_in[3];
  const float* b_hh0   = (const float*)d_in[4];
  const float* w_ih1   = (const float*)d_in[5];
  const float* w_hh1   = (const float*)d_in[6];
  const float* b_ih1   = (const float*)d_in[7];
  const float* b_hh1   = (const float*)d_in[8];
  const float* attn_w1 = (const float*)d_in[9];
  const float* attn_b1 = (const float*)d_in[10];
  const float* attn_w2 = (const float*)d_in[11];
  const float* attn_b2 = (const float*)d_in[12];
  const float* ln_g    = (const float*)d_in[13];
  const float* ln_b    = (const float*)d_in[14];
  const float* head_w1 = (const float*)d_in[15];
  const float* head_b1 = (const float*)d_in[16];
  const float* head_w2 = (const float*)d_in[17];
  const float* head_b2 = (const float*)d_in[18];
  hipLaunchKernelGGL(gru_attn_fused, dim3(256), dim3(640), 0, stream,
                     x, w_ih0, w_hh0, b_ih0, b_hh0, w_ih1, w_hh1, b_ih1, b_hh1,
                     attn_w1, attn_b1, attn_w2, attn_b2, ln_g, ln_b,
                     head_w1, head_b1, head_w2, head_b2, (float*)d_out);
}

// Round 6
// 1625.862 us; speedup vs baseline: 1.8970x; 1.3032x over previous
//
#include <hip/hip_runtime.h>
#include <math.h>

#define TS 2048

typedef float f32x2 __attribute__((ext_vector_type(2)));

// Column swizzle: each 16-float quarter padded to stride 24 (96B). Quarter bases
// hit banks {0,24,16,8} -> 4 disjoint 4-bank groups -> conflict-free reads.
#define SWZ(c) ((((c)>>4)*24) + ((c)&15))
#define RSTR 96

// LDS float offsets
#define XT0  0       // x tile 0: [64 t][96]
#define XT1  6144    // x tile 1
#define H0O  12288   // h0[2][96] parity double-buffer
#define H1O  12480   // h1[2][96]
#define SCRO 12672   // epilogue scratch
#define LDSF 12772

// Raw barrier: LDS-ordering only, NO vmcnt drain (stage prefetch stays in flight)
#define BAR() do { asm volatile("s_waitcnt lgkmcnt(0)" ::: "memory"); __builtin_amdgcn_s_barrier(); } while(0)

union F4 { float4 f4; f32x2 h[2]; };

__device__ __forceinline__ float sigmoidf_(float v){ return __builtin_amdgcn_rcpf(1.0f+__expf(-v)); }
__device__ __forceinline__ float tanhf_(float v){
  v = fminf(15.0f, fmaxf(-15.0f, v));
  const float e = __expf(2.0f*v);
  return (e-1.0f)*__builtin_amdgcn_rcpf(e+1.0f);
}
__device__ __forceinline__ void pkfma(f32x2& acc, const f32x2 w, const f32x2 v){
  acc = __builtin_elementwise_fma(w, v, acc);
}
// quad (4-lane) sum via DPP quad_perm butterflies (VALU pipe)
__device__ __forceinline__ float qadd2(float v){
  float a = v + __int_as_float(__builtin_amdgcn_update_dpp(0, __float_as_int(v), 0xB1, 0xF, 0xF, true));
  return a + __int_as_float(__builtin_amdgcn_update_dpp(0, __float_as_int(a), 0x4E, 0xF, 0xF, true));
}
// full 64-lane sum via DPP row_shr scan + row_bcast, result uniform via readlane(63)
__device__ __forceinline__ float wsum64(float v){
  v += __int_as_float(__builtin_amdgcn_update_dpp(0, __float_as_int(v), 0x111, 0xF, 0xF, true)); // row_shr:1
  v += __int_as_float(__builtin_amdgcn_update_dpp(0, __float_as_int(v), 0x112, 0xF, 0xF, true)); // row_shr:2
  v += __int_as_float(__builtin_amdgcn_update_dpp(0, __float_as_int(v), 0x114, 0xF, 0xF, true)); // row_shr:4
  v += __int_as_float(__builtin_amdgcn_update_dpp(0, __float_as_int(v), 0x118, 0xF, 0xF, true)); // row_shr:8
  v += __int_as_float(__builtin_amdgcn_update_dpp(0, __float_as_int(v), 0x142, 0xA, 0xF, true)); // row_bcast15 -> rows 1,3
  v += __int_as_float(__builtin_amdgcn_update_dpp(0, __float_as_int(v), 0x143, 0xC, 0xF, true)); // row_bcast31 -> rows 2,3
  return __int_as_float(__builtin_amdgcn_readlane(__float_as_int(v), 63));
}

// 24-pkfma triple dot over a 64-float (16 per lane-quarter) LDS vector
__device__ __forceinline__ void dot3(const float* base, const f32x2* w0, const f32x2* w1,
                                     const f32x2* w2, f32x2& a0, f32x2& a1, f32x2& a2){
  #pragma unroll
  for (int i=0;i<4;i++){
    F4 u; u.f4 = ((const float4*)base)[i];
    pkfma(a0, w0[2*i], u.h[0]); pkfma(a0, w0[2*i+1], u.h[1]);
    pkfma(a1, w1[2*i], u.h[0]); pkfma(a1, w1[2*i+1], u.h[1]);
    pkfma(a2, w2[2*i], u.h[0]); pkfma(a2, w2[2*i+1], u.h[1]);
  }
}

// 10 waves = 640 threads:
//   waves 0-3: layer-0. wave -> 16 rows; lane = 4*row_local + quarter q (16 cols each).
//   waves 4-7: layer-1, same.
//   wave 8   : attention (lane o: full 64-dot vs attn_w1[o]).
//   wave 9   : x stage.
// Skew: iter it computes L0@t=it, L1@t=it-2, attn@t=it-3. All LDS reads from
// parity rb=it&1, writes to wb. ih-side dots computed one iter early (stash).
__global__ __launch_bounds__(640, 1)
void gru_attn_fused(const float* __restrict__ x,
                    const float* __restrict__ w_ih0, const float* __restrict__ w_hh0,
                    const float* __restrict__ b_ih0, const float* __restrict__ b_hh0,
                    const float* __restrict__ w_ih1, const float* __restrict__ w_hh1,
                    const float* __restrict__ b_ih1, const float* __restrict__ b_hh1,
                    const float* __restrict__ attn_w1, const float* __restrict__ attn_b1,
                    const float* __restrict__ attn_w2, const float* __restrict__ attn_b2,
                    const float* __restrict__ ln_g, const float* __restrict__ ln_b,
                    const float* __restrict__ head_w1, const float* __restrict__ head_b1,
                    const float* __restrict__ head_w2, const float* __restrict__ head_b2,
                    float* __restrict__ out)
{
  __shared__ float lds[LDSF];
  const int tid  = threadIdx.x;
  const int b    = blockIdx.x;
  const int wid  = tid >> 6;
  const int lane = tid & 63;
  const float* xb = x + (size_t)b * 64 * TS;

  const bool isGate = (wid < 8);
  const bool isAttn = (wid == 8);
  const int  l      = (wid >> 2) & 1;
  const int  row    = ((wid & 3) << 4) + (lane >> 2);  // 0..63
  const int  q16    = (lane & 3) << 4;                 // col offset (global)
  const int  q24    = (lane & 3) * 24;                 // col offset (padded LDS)
  const int  srow   = SWZ(row);

  // W2 roles: gate: [0..7]=ih_r [8..15]=ih_z [16..23]=ih_n [24..31]=hh_r [32..39]=hh_z [40..47]=hh_n
  //           attn: [0..31] = attn_w1 row; stage: [0..31] = x pipeline
  f32x2 W2[48];
  float brz_r=0.f, brz_z=0.f, bin_=0.f, bhn_=0.f, b1o=0.f, w2o=0.f, b2v=0.f;

  if (isGate) {
    const float* bih = l ? w_ih1 : w_ih0;
    const float* bhh = l ? w_hh1 : w_hh0;
    #pragma unroll
    for (int i=0;i<8;i++){
      W2[i]    = *(const f32x2*)(bih + (      row)*64 + q16 + 2*i);
      W2[8+i]  = *(const f32x2*)(bih + ( 64 + row)*64 + q16 + 2*i);
      W2[16+i] = *(const f32x2*)(bih + (128 + row)*64 + q16 + 2*i);
      W2[24+i] = *(const f32x2*)(bhh + (      row)*64 + q16 + 2*i);
      W2[32+i] = *(const f32x2*)(bhh + ( 64 + row)*64 + q16 + 2*i);
      W2[40+i] = *(const f32x2*)(bhh + (128 + row)*64 + q16 + 2*i);
    }
    // Pin weights in VGPRs: breaks rematerialization (compiler was re-loading
    // weights from global every iteration; VGPR_Count 80 < 96 weight floats).
    #pragma unroll
    for (int k=0;k<48;k++) asm volatile("" : "+v"(W2[k]));
    const float* bi = l ? b_ih1 : b_ih0;
    const float* bh = l ? b_hh1 : b_hh0;
    brz_r = bi[row]      + bh[row];
    brz_z = bi[64+row]   + bh[64+row];
    bin_  = bi[128+row];
    bhn_  = bh[128+row];
  } else if (isAttn) {
    #pragma unroll
    for (int i=0;i<32;i++) W2[i] = *(const f32x2*)(attn_w1 + lane*64 + 2*i);
    #pragma unroll
    for (int k=0;k<32;k++) asm volatile("" : "+v"(W2[k]));
    b1o = attn_b1[lane]; w2o = attn_w2[lane]; b2v = attn_b2[0];
  }

  // prologue: zero h buffers, stage x tile 0 (swizzled transpose)
  if (tid < 384) lds[H0O + tid] = 0.f;
  if (tid < 256) {
    const int c = tid >> 2, t0 = (tid & 3) << 4;
    const int sc = SWZ(c);
    #pragma unroll
    for (int m=0;m<4;m++){
      float4 v = *(const float4*)(xb + c*TS + t0 + 4*m);
      lds[XT0 + (t0+4*m+0)*RSTR + sc] = v.x;
      lds[XT0 + (t0+4*m+1)*RSTR + sc] = v.y;
      lds[XT0 + (t0+4*m+2)*RSTR + sc] = v.z;
      lds[XT0 + (t0+4*m+3)*RSTR + sc] = v.w;
    }
  }
  __syncthreads();

  f32x2 stR={0.f,0.f}, stZ={0.f,0.f}, stN={0.f,0.f};   // ih-dot stash (gate waves)
  float am = -1e30f, aZ = 0.f, aP = 0.f;               // online softmax (wave 8)

  // pre-loop: L0's ih stash for t=0 (x tile 0 staged above)
  if (isGate && l==0) {
    const float* xv = &lds[XT0 + q24];
    dot3(xv, W2+0, W2+8, W2+16, stR, stZ, stN);
  }

  #pragma unroll 1
  for (int it = 0; it < TS + 3; ++it) {
    const int rb   = it & 1;
    const int wb   = rb ^ 1;
    const int tile = it >> 6;
    const int xsel = tile & 1;
    const int tt   = it & 63;

    if (isGate) {
      const bool act = (l==0) ? (it < TS) : (it >= 2 && it <= TS+1);
      if (act) {
        const int hbo = l ? H1O : H0O;
        const float* hv = &lds[hbo + rb*RSTR + q24];
        f32x2 cr={0.f,0.f}, cz={0.f,0.f}, cn={0.f,0.f};
        dot3(hv, W2+24, W2+32, W2+40, cr, cz, cn);
        const float sr = qadd2((stR.x+stR.y)+(cr.x+cr.y));
        const float sz = qadd2((stZ.x+stZ.y)+(cz.x+cz.y));
        const float xn = qadd2(stN.x+stN.y);
        const float hn = qadd2(cn.x+cn.y);
        const float r  = sigmoidf_(sr + brz_r);
        const float z  = sigmoidf_(sz + brz_z);
        const float n  = tanhf_((xn + bin_) + r*(hn + bhn_));
        const float hold = lds[hbo + rb*RSTR + srow];
        if ((lane & 3) == 0) lds[hbo + wb*RSTR + srow] = n + z*(hold - n);
      }
      // ih stash for the NEXT iteration's timestep (inputs already in LDS)
      if (l==0) {
        if (it+1 < TS) {
          const int ix = it+1;
          const float* xv = &lds[(((ix>>6)&1)?XT1:XT0) + (ix&63)*RSTR + q24];
          stR=(f32x2){0.f,0.f}; stZ=(f32x2){0.f,0.f}; stN=(f32x2){0.f,0.f};
          dot3(xv, W2+0, W2+8, W2+16, stR, stZ, stN);
        }
      } else {
        if (it >= 1 && it <= TS) {   // ih-dot on h0(it-1) for t'=it-1
          const float* gv = &lds[H0O + rb*RSTR + q24];
          stR=(f32x2){0.f,0.f}; stZ=(f32x2){0.f,0.f}; stN=(f32x2){0.f,0.f};
          dot3(gv, W2+0, W2+8, W2+16, stR, stZ, stN);
        }
      }
    } else if (isAttn) {
      if (it >= 3 && it <= TS+2) {
        const float* hv = &lds[H1O + rb*RSTR];
        f32x2 p0={0.f,0.f}, p1={0.f,0.f};
        #pragma unroll
        for (int qq=0;qq<4;qq++){
          const float4* hp = (const float4*)(hv + qq*24);
          #pragma unroll
          for (int i=0;i<4;i++){
            F4 u; u.f4 = hp[i];
            pkfma(p0, W2[qq*8+2*i],   u.h[0]);
            pkfma(p1, W2[qq*8+2*i+1], u.h[1]);
          }
        }
        const float a  = tanhf_(((p0.x+p0.y)+(p1.x+p1.y)) + b1o);
        const float s  = wsum64(w2o * a) + b2v;
        const float h1v = lds[H1O + rb*RSTR + SWZ(lane)];
        const float mn = fmaxf(am, s);
        const float sc = __expf(am - mn);
        const float p  = __expf(s - mn);
        aZ = aZ*sc + p;
        aP = aP*sc + p*h1v;
        am = mn;
      }
    } else { // stage wave (wid 9)
      if (tile <= 30) {
        if (tt == 0) {
          const float* src = xb + (lane>>4)*TS + (tile+1)*64 + ((lane&15)<<2);
          #pragma unroll
          for (int k=0;k<16;k++){
            F4 u; u.f4 = *(const float4*)(src + (size_t)k*4*TS);
            W2[2*k] = u.h[0]; W2[2*k+1] = u.h[1];
          }
        } else if (tt == 32) {
          float* dst = &lds[xsel ? XT0 : XT1];
          const int c0 = lane >> 4, t4 = (lane & 15) << 2;
          #pragma unroll
          for (int k=0;k<16;k++){
            const int oc = (k>>2)*24 + 4*(k&3) + c0;   // SWZ(4k + c0)
            F4 u; u.h[0] = W2[2*k]; u.h[1] = W2[2*k+1];
            dst[(t4+0)*RSTR + oc] = u.f4.x;
            dst[(t4+1)*RSTR + oc] = u.f4.y;
            dst[(t4+2)*RSTR + oc] = u.f4.z;
            dst[(t4+3)*RSTR + oc] = u.f4.w;
          }
        }
      }
    }
    BAR();
  }

  // ---------------- epilogue ----------------
  if (isAttn) {
    const float pooled = aP / aZ;
    float mu = pooled;
    #pragma unroll
    for (int m=1;m<64;m<<=1) mu += __shfl_xor(mu, m, 64);
    mu *= (1.0f/64.0f);
    const float d = pooled - mu;
    float var = d*d;
    #pragma unroll
    for (int m=1;m<64;m<<=1) var += __shfl_xor(var, m, 64);
    var *= (1.0f/64.0f);
    const float y = d * rsqrtf(var + 1e-5f) * ln_g[lane] + ln_b[lane];
    lds[SCRO + lane] = y;
  }
  __syncthreads();
  if (tid < 32) {
    const float* hw = head_w1 + tid*64;
    float acc = head_b1[tid];
    #pragma unroll
    for (int k=0;k<16;k++){
      const float4 w4 = ((const float4*)hw)[k];
      acc += w4.x*lds[SCRO+4*k+0] + w4.y*lds[SCRO+4*k+1]
           + w4.z*lds[SCRO+4*k+2] + w4.w*lds[SCRO+4*k+3];
    }
    const float u = 0.5f*acc*(1.0f + erff(acc*0.70710678118654752f)); // exact GELU
    lds[SCRO + 64 + tid] = u;
  }
  __syncthreads();
  if (tid < 8) {
    const float* hw = head_w2 + tid*32;
    float acc = head_b2[tid];
    #pragma unroll
    for (int k=0;k<8;k++){
      const float4 w4 = ((const float4*)hw)[k];
      acc += w4.x*lds[SCRO+64+4*k+0] + w4.y*lds[SCRO+64+4*k+1]
           + w4.z*lds[SCRO+64+4*k+2] + w4.w*lds[SCRO+64+4*k+3];
    }
    out[b*8 + tid] = acc;
  }
}

extern "C" void kernel_launch(void* const* d_in, const int* in_sizes, int n_in,
                              void* d_out, int out_size, void* d_ws, size_t ws_size,
                              hipStream_t stream) {
  (void)in_sizes; (void)n_in; (void)d_ws; (void)ws_size; (void)out_size;
  const float* x       = (const float*)d_in[0];
  const float* w_ih0   = (const float*)d_in[1];
  const float* w_hh0   = (const float*)d_in[2];
  const float* b_ih0   = (const float*)d_in[3];
  const float* b_hh0   = (const float*)d_in[4];
  const float* w_ih1   = (const float*)d_in[5];
  const float* w_hh1   = (const float*)d_in[6];
  const float* b_ih1   = (const float*)d_in[7];
  const float* b_hh1   = (const float*)d_in[8];
  const float* attn_w1 = (const float*)d_in[9];
  const float* attn_b1 = (const float*)d_in[10];
  const float* attn_w2 = (const float*)d_in[11];
  const float* attn_b2 = (const float*)d_in[12];
  const float* ln_g    = (const float*)d_in[13];
  const float* ln_b    = (const float*)d_in[14];
  const float* head_w1 = (const float*)d_in[15];
  const float* head_b1 = (const float*)d_in[16];
  const float* head_w2 = (const float*)d_in[17];
  const float* head_b2 = (const float*)d_in[18];
  hipLaunchKernelGGL(gru_attn_fused, dim3(256), dim3(640), 0, stream,
                     x, w_ih0, w_hh0, b_ih0, b_hh0, w_ih1, w_hh1, b_ih1, b_hh1,
                     attn_w1, attn_b1, attn_w2, attn_b2, ln_g, ln_b,
                     head_w1, head_b1, head_w2, head_b2, (float*)d_out);
}